// Round 2
// baseline (315.274 us; speedup 1.0000x reference)
//
#include <hip/hip_runtime.h>
#include <cstddef>

#define B_ 32
#define C_ 32
#define L_ 16384
#define H_ 4
#define DH_ 8
#define NB_ 3
#define DOUT_ 10
#define SEG_ 512
#define S_ (L_/SEG_)   // 32 segments for the standalone stats pass (block 0 input)
#define S2_ (L_/256)   // 64 segments for fused stats (one per block_kernel WG)

#define TILE 256
#define AST  40    // A_lds row stride (halfs): 80 B/row -> 16B-aligned b128 frag reads
#define OST  260   // O16 row stride (floats): 16B-aligned f32x4, banks spread by +4

typedef _Float16 f16_t;
typedef _Float16 f16x2 __attribute__((ext_vector_type(2)));
typedef _Float16 f16x8 __attribute__((ext_vector_type(8)));
typedef float    f32x4 __attribute__((ext_vector_type(4)));

// Branch-free gelu via Abramowitz-Stegun 7.1.26 erf approximation (|eps|<=1.5e-7).
__device__ __forceinline__ float gelu_f(float x){
    const float z  = fabsf(x) * 0.70710678118654752440f;
    const float t  = __builtin_amdgcn_rcpf(fmaf(0.3275911f, z, 1.0f));
    const float e  = __expf(-z * z);
    float p = fmaf(t, 1.061405429f, -1.453152027f);
    p = fmaf(t, p, 1.421413741f);
    p = fmaf(t, p, -0.284496736f);
    p = fmaf(t, p, 0.254829592f);
    const float erfz = 1.0f - p * t * e;          // erf(|x|/sqrt(2))
    const float phi  = fmaf(copysignf(erfz, x), 0.5f, 0.5f);
    return x * phi;
}

#define RED_MAX32(v) do{ v = fmaxf(v, __shfl_xor(v,1));  v = fmaxf(v, __shfl_xor(v,2)); \
                         v = fmaxf(v, __shfl_xor(v,4));  v = fmaxf(v, __shfl_xor(v,8)); \
                         v = fmaxf(v, __shfl_xor(v,16)); }while(0)
#define RED_SUM32(v) do{ v += __shfl_xor(v,1);  v += __shfl_xor(v,2); \
                         v += __shfl_xor(v,4);  v += __shfl_xor(v,8); \
                         v += __shfl_xor(v,16); }while(0)

// ---- stats: per (b, head, seg) partial max / sumexp / kv over a 512-pos segment ----
// Only used for the raw input x (block 0). Blocks 1,2 get their stats fused into
// the previous block_kernel's epilogue (O16 already holds the output channel-major).
__global__ __launch_bounds__(256) void stats_kernel(const float* __restrict__ h,
                                                    float* __restrict__ part){
    const int seg = blockIdx.x;
    const int hd  = blockIdx.y;
    const int b   = blockIdx.z;
    const int t   = threadIdx.x;
    const int d   = t >> 5;   // 0..7  (feature within head); wave-half owns one d
    const int j   = t & 31;   // 0..31 (position lane)

    __shared__ float tile[8][SEG_];   // 16 KB
    __shared__ float sm[8];

    const float* hb = h + (size_t)b * ((size_t)C_*L_) + (size_t)(hd*DH_)*L_ + (size_t)seg*SEG_;

    // stage 8 x 512 tile (coalesced float4; each element fetched exactly once)
    for (int f = t; f < 8*SEG_/4; f += 256){
        const int row = f >> 7;            // 128 float4 per row
        const int c4  = (f & 127) << 2;
        *(f32x4*)&tile[row][c4] = *(const f32x4*)&hb[(size_t)row*L_ + c4];
    }
    __syncthreads();

    // pass 1: per-d max
    float m = -INFINITY;
    #pragma unroll
    for (int i = 0; i < SEG_/32; i++) m = fmaxf(m, tile[d][j + 32*i]);
    RED_MAX32(m);
    if (j == 0) sm[d] = m;
    const float m_d = m;

    // pass 2: sumexp + kv partials (referenced to segment max)
    float s = 0.0f;
    float kv[8];
    #pragma unroll
    for (int e = 0; e < 8; e++) kv[e] = 0.0f;
    #pragma unroll
    for (int i = 0; i < SEG_/32; i++){
        const int k = j + 32*i;
        const float ek = __expf(tile[d][k] - m_d);
        s += ek;
        #pragma unroll
        for (int e = 0; e < 8; e++) kv[e] = fmaf(ek, tile[e][k], kv[e]);
    }
    RED_SUM32(s);
    #pragma unroll
    for (int e = 0; e < 8; e++){ RED_SUM32(kv[e]); }
    __syncthreads();

    float* po = part + (size_t)((b*H_ + hd)*S_ + seg) * 80;
    if (j == 0){
        po[8 + d] = s;
        #pragma unroll
        for (int e = 0; e < 8; e++) po[16 + d*8 + e] = kv[e];
    }
    if (t < 8) po[t] = sm[t];
}

// ---- merge segment partials -> normalized kvn[b][head][d][e] = kv/s ----
// 256 threads: 4 segment-groups in parallel + LDS tree (the 64-thread serial
// version was a latency-bound dependent loop over all segments).
__global__ __launch_bounds__(256) void merge_kernel(const float* __restrict__ part,
                                                    float* __restrict__ kvn,
                                                    int nseg){
    const int bh = blockIdx.x;              // 0..B*H-1
    const int t  = threadIdx.x & 63;        // (d,e)
    const int g  = threadIdx.x >> 6;        // 0..3 segment group
    const int d  = t >> 3;
    const float* p = part + (size_t)bh * nseg * 80;
    __shared__ float r1[4][64], r2[4][64];

    float M = -INFINITY;
    for (int s2 = g; s2 < nseg; s2 += 4) M = fmaxf(M, p[s2*80 + d]);
    r1[g][t] = M;
    __syncthreads();
    M = fmaxf(fmaxf(r1[0][t], r1[1][t]), fmaxf(r1[2][t], r1[3][t]));
    __syncthreads();

    float ssum = 0.0f, kvsum = 0.0f;
    for (int s2 = g; s2 < nseg; s2 += 4){
        const float sc = __expf(p[s2*80 + d] - M);
        ssum  += p[s2*80 + 8  + d] * sc;
        kvsum += p[s2*80 + 16 + t] * sc;
    }
    r1[g][t] = ssum; r2[g][t] = kvsum;
    __syncthreads();
    if (g == 0){
        ssum  = r1[0][t]+r1[1][t]+r1[2][t]+r1[3][t];
        kvsum = r2[0][t]+r2[1][t]+r2[2][t]+r2[3][t];
        kvn[(size_t)bh*64 + t] = kvsum / ssum;
    }
}

// ---- per-position attention (fp32) + FC1/FC2 via f16 MFMA ----
// LDS 26112 (Ash aliased with O16) -> 6 WG/CU by LDS.
// OCCUPANCY NOTE (R1 post-mortem): waves_per_eu(6,8) crushed VGPRs 68->40,
// forcing per-thread scratch spills: +54 MB write / +27 MB fetch PER DISPATCH
// of pure spill traffic, dur 41->70 us. The live set needs ~70-85 VGPRs.
// waves_per_eu(5) caps at 102 VGPRs (>= natural allocation, no spill) while
// still guaranteeing 5 waves/EU = 20 waves/CU (vs baseline's 12).
// STATS: compute next block's per-segment softmax partials straight from O16
// (channel-major fp32, bit-identical to hout) -- removes the standalone 64 MB
// stats pass for blocks 1,2.
// MFMA layouts (m89/m91-verified conventions):
//   A-frag: lane holds A[m=lane&15][k=(lane>>4)*8+j], 8 halfs contiguous
//   B-frag: lane holds B[k=(lane>>4)*8+j][n=lane&15]  (stored as Bsh[n][k])
//   C/D:    col=lane&15, row=(lane>>4)*4+reg
template<bool LAST, bool STATS>
__global__ __launch_bounds__(256)
__attribute__((amdgpu_waves_per_eu(5)))
void block_kernel(const float* hin,
                  float* hout,
                  const float* __restrict__ kvn,
                  const float* __restrict__ W1,
                  const float* __restrict__ b1,
                  const float* __restrict__ W2,
                  const float* __restrict__ b2,
                  float* __restrict__ pooled,
                  float* __restrict__ partout){
    __shared__ __align__(16) char AObuf[TILE*AST*2];   // 20480 B, union:
    f16_t* const Ash = (f16_t*)AObuf;                  //   A matrix [pos][k] halfs
    float* const O16 = (float*)AObuf;                  //   16-chan transpose buffer (16640 B)
    __shared__ f16_t Bsh1[32*AST];      // 2560 B: W1 as [n][k]
    __shared__ f16_t Bsh2[32*AST];      // 2560 B
    __shared__ float sb1[32], sb2[32];
    __shared__ float pool[32];

    const int tid = threadIdx.x;
    const int b   = blockIdx.y;
    const int l0  = blockIdx.x * TILE;
    const int l   = l0 + tid;
    const size_t base = (size_t)b * ((size_t)C_*L_);
    const float* kv = kvn + (size_t)b * (H_*DH_*DH_);

    // stage weights f32->f16 into B-layout: Bsh[n][k] = W[k*32+n]
    for (int i = tid; i < 1024; i += 256){
        const int k = i >> 5, n = i & 31;
        Bsh1[n*AST + k] = (f16_t)W1[i];
        Bsh2[n*AST + k] = (f16_t)W2[i];
    }
    if (tid < 32){ sb1[tid] = b1[tid]; sb2[tid] = b2[tid]; }
    if (LAST && tid < 32) pool[tid] = 0.0f;

    // ---- phase 1: per-thread fp32 attention ----
    float h[32];
    #pragma unroll
    for (int c = 0; c < 32; c++) h[c] = hin[base + (size_t)c*L_ + l];

    float attn[32];
    #pragma unroll
    for (int hh = 0; hh < 4; hh++){
        float mq = h[hh*8];
        #pragma unroll
        for (int d2 = 1; d2 < 8; d2++) mq = fmaxf(mq, h[hh*8 + d2]);
        float es[8]; float qs = 0.f;
        #pragma unroll
        for (int d2 = 0; d2 < 8; d2++){ es[d2] = __expf(h[hh*8 + d2] - mq); qs += es[d2]; }
        const float inv = __builtin_amdgcn_rcpf(qs);
        #pragma unroll
        for (int e = 0; e < 8; e++){
            float a = 0.f;
            #pragma unroll
            for (int d2 = 0; d2 < 8; d2++) a += es[d2] * kv[hh*64 + d2*8 + e];
            attn[hh*8 + e] = a * inv;
        }
    }

    // attn -> f16 A matrix in LDS: Ash[pos=tid][k]
    #pragma unroll
    for (int k2 = 0; k2 < 32; k2 += 2){
        f16x2 pr = { (f16_t)attn[k2], (f16_t)attn[k2+1] };
        *(f16x2*)&Ash[tid*AST + k2] = pr;
    }
    __syncthreads();   // weights + A visible to all

    // ---- phase 2: MFMA FCs ----
    const int wv   = tid >> 6;       // wave 0..3 -> positions [wv*64, wv*64+64)
    const int lane = tid & 63;
    const int lr   = lane & 15;      // A-row / D-col index
    const int lk   = lane >> 4;      // k-group 0..3
    const f32x4 zero = {0.f, 0.f, 0.f, 0.f};

    f16x8 a[4], bw[2];
    f32x4 d[8];

    // FC1
    #pragma unroll
    for (int mt = 0; mt < 4; mt++)
        a[mt] = *(const f16x8*)&Ash[(wv*64 + mt*16 + lr)*AST + lk*8];
    #pragma unroll
    for (int nt = 0; nt < 2; nt++)
        bw[nt] = *(const f16x8*)&Bsh1[(nt*16 + lr)*AST + lk*8];
    #pragma unroll
    for (int nt = 0; nt < 2; nt++)
        #pragma unroll
        for (int mt = 0; mt < 4; mt++)
            d[nt*4+mt] = __builtin_amdgcn_mfma_f32_16x16x32_f16(a[mt], bw[nt], zero, 0, 0, 0);

    // bias + gelu + write back as A2 (in-place over Ash; rows are wave-private)
    #pragma unroll
    for (int nt = 0; nt < 2; nt++){
        const float bias = sb1[nt*16 + lr];
        #pragma unroll
        for (int mt = 0; mt < 4; mt++){
            #pragma unroll
            for (int r = 0; r < 4; r++){
                const float v = gelu_f(d[nt*4+mt][r] + bias);
                Ash[(wv*64 + mt*16 + lk*4 + r)*AST + (nt*16 + lr)] = (f16_t)v;
            }
        }
    }
    __syncthreads();

    // FC2
    #pragma unroll
    for (int mt = 0; mt < 4; mt++)
        a[mt] = *(const f16x8*)&Ash[(wv*64 + mt*16 + lr)*AST + lk*8];
    #pragma unroll
    for (int nt = 0; nt < 2; nt++)
        bw[nt] = *(const f16x8*)&Bsh2[(nt*16 + lr)*AST + lk*8];
    #pragma unroll
    for (int nt = 0; nt < 2; nt++)
        #pragma unroll
        for (int mt = 0; mt < 4; mt++)
            d[nt*4+mt] = __builtin_amdgcn_mfma_f32_16x16x32_f16(a[mt], bw[nt], zero, 0, 0, 0);

    // bias + gelu on D (fp32)
    #pragma unroll
    for (int nt = 0; nt < 2; nt++){
        const float bias = sb2[nt*16 + lr];
        #pragma unroll
        for (int mt = 0; mt < 4; mt++)
            #pragma unroll
            for (int r = 0; r < 4; r++)
                d[nt*4+mt][r] = gelu_f(d[nt*4+mt][r] + bias);
    }

    if (!LAST){
        // transpose D -> [chan][pos] via LDS (aliases Ash; Ash reads all complete
        // before the leading barrier). While the O16 half-tile is live, also
        // compute next-block stats partials from it (fused stats).
        #pragma unroll
        for (int nt = 0; nt < 2; nt++){
            __syncthreads();   // previous O16 consumers done / Ash dead
            #pragma unroll
            for (int mt = 0; mt < 4; mt++)
                *(f32x4*)&O16[lr*OST + wv*64 + mt*16 + lk*4] = d[nt*4+mt];
            __syncthreads();
            #pragma unroll
            for (int c = 0; c < 16; c++)
                hout[base + (size_t)(nt*16 + c)*L_ + l0 + tid] = O16[c*OST + tid];

            if constexpr (STATS){
                // O16[r16][pos]: channels nt*16+r16, heads nt*2 + (r16>>3).
                // Same math as stats_kernel, segment = this WG's 256 positions.
                const int sd = tid >> 5;   // 0..7 feature
                const int sj = tid & 31;   // position lane
                #pragma unroll
                for (int hh2 = 0; hh2 < 2; hh2++){
                    const int row = hh2*8 + sd;
                    float m = -INFINITY;
                    #pragma unroll
                    for (int i = 0; i < 8; i++) m = fmaxf(m, O16[row*OST + sj + 32*i]);
                    RED_MAX32(m);
                    float s = 0.0f;
                    float kvp[8];
                    #pragma unroll
                    for (int e = 0; e < 8; e++) kvp[e] = 0.0f;
                    #pragma unroll
                    for (int i = 0; i < 8; i++){
                        const int k = sj + 32*i;
                        const float ek = __expf(O16[row*OST + k] - m);
                        s += ek;
                        #pragma unroll
                        for (int e = 0; e < 8; e++)
                            kvp[e] = fmaf(ek, O16[(hh2*8+e)*OST + k], kvp[e]);
                    }
                    RED_SUM32(s);
                    #pragma unroll
                    for (int e = 0; e < 8; e++){ RED_SUM32(kvp[e]); }
                    if (sj == 0){
                        float* po = partout +
                            (size_t)((b*H_ + nt*2 + hh2)*S2_ + blockIdx.x) * 80;
                        po[sd]     = m;
                        po[8 + sd] = s;
                        #pragma unroll
                        for (int e = 0; e < 8; e++) po[16 + sd*8 + e] = kvp[e];
                    }
                }
            }
        }
    } else {
        // pooled += sum over this WG's 256 positions
        __syncthreads();   // pool[] initialized
        #pragma unroll
        for (int nt = 0; nt < 2; nt++){
            float ps = 0.f;
            #pragma unroll
            for (int mt = 0; mt < 4; mt++)
                ps += d[nt*4+mt][0] + d[nt*4+mt][1] + d[nt*4+mt][2] + d[nt*4+mt][3];
            atomicAdd(&pool[nt*16 + lr], ps);
        }
        __syncthreads();
        if (tid < 32) atomicAdd(&pooled[b*32 + tid], pool[tid]);
    }
}

// ---- head: pooled/L -> Wh+bh -> BN(eval) -> gelu -> Wf+bf ----
__global__ __launch_bounds__(1024) void head_kernel(const float* __restrict__ pooled,
                                                    const float* __restrict__ Wh,
                                                    const float* __restrict__ bh,
                                                    const float* __restrict__ gam,
                                                    const float* __restrict__ bet,
                                                    const float* __restrict__ mean,
                                                    const float* __restrict__ var,
                                                    const float* __restrict__ Wf,
                                                    const float* __restrict__ bf,
                                                    float* __restrict__ out){
    __shared__ float y2[32][32];
    const int t = threadIdx.x;      // 0..1023
    const int b = t >> 5, c = t & 31;
    float a = bh[c];
    const float invL = 1.0f / (float)L_;
    #pragma unroll
    for (int d = 0; d < 32; d++) a += (pooled[b*32 + d] * invL) * Wh[d*32 + c];
    a = (a - mean[c]) * rsqrtf(var[c] + 1e-5f) * gam[c] + bet[c];
    y2[b][c] = gelu_f(a);
    __syncthreads();
    if (t < B_*DOUT_){
        const int b2 = t / DOUT_, j = t % DOUT_;
        float r = bf[j];
        #pragma unroll
        for (int c2 = 0; c2 < 32; c2++) r += y2[b2][c2] * Wf[c2*DOUT_ + j];
        out[t] = r;
    }
}

extern "C" void kernel_launch(void* const* d_in, const int* in_sizes, int n_in,
                              void* d_out, int out_size, void* d_ws, size_t ws_size,
                              hipStream_t stream){
    (void)in_sizes; (void)n_in; (void)out_size; (void)ws_size;
    const float* x    = (const float*)d_in[0];
    const float* fW1  = (const float*)d_in[1];
    const float* fb1  = (const float*)d_in[2];
    const float* fW2  = (const float*)d_in[3];
    const float* fb2  = (const float*)d_in[4];
    const float* Wh   = (const float*)d_in[5];
    const float* bh   = (const float*)d_in[6];
    const float* gam  = (const float*)d_in[7];
    const float* bet  = (const float*)d_in[8];
    const float* mean = (const float*)d_in[9];
    const float* var  = (const float*)d_in[10];
    const float* Wf   = (const float*)d_in[11];
    const float* bf   = (const float*)d_in[12];
    float* out = (float*)d_out;

    float* hbuf   = (float*)d_ws;                          // B*C*L floats (64 MB)
    float* part   = hbuf + (size_t)B_*C_*L_;               // B*H*S2_*80 (~2.6 MB)
    float* kvn    = part + (size_t)B_*H_*S2_*80;           // B*H*64
    float* pooled = kvn  + (size_t)B_*H_*64;               // B*C

    hipMemsetAsync(pooled, 0, B_*C_*sizeof(float), stream);

    dim3 sgrid(S_, H_, B_);
    dim3 bgrid(L_/TILE, B_);

    // block 0 (input = x, output -> hbuf; fused stats for block 1 -> part)
    stats_kernel<<<sgrid, 256, 0, stream>>>(x, part);
    merge_kernel<<<B_*H_, 256, 0, stream>>>(part, kvn, S_);
    block_kernel<false, true><<<bgrid, 256, 0, stream>>>(x, hbuf, kvn,
        fW1, fb1, fW2, fb2, nullptr, part);
    // block 1 (in-place on hbuf; fused stats for block 2 -> part)
    merge_kernel<<<B_*H_, 256, 0, stream>>>(part, kvn, S2_);
    block_kernel<false, true><<<bgrid, 256, 0, stream>>>(hbuf, hbuf, kvn,
        fW1 + C_*C_, fb1 + C_, fW2 + C_*C_, fb2 + C_, nullptr, part);
    // block 2 (no h write; reduce into pooled)
    merge_kernel<<<B_*H_, 256, 0, stream>>>(part, kvn, S2_);
    block_kernel<true, false><<<bgrid, 256, 0, stream>>>(hbuf, nullptr, kvn,
        fW1 + 2*C_*C_, fb1 + 2*C_, fW2 + 2*C_*C_, fb2 + 2*C_, pooled, nullptr);

    head_kernel<<<1, 1024, 0, stream>>>(pooled, Wh, bh, gam, bet, mean, var, Wf, bf, out);
}

// Round 3
// 292.718 us; speedup vs baseline: 1.0771x; 1.0771x over previous
//
#include <hip/hip_runtime.h>
#include <cstddef>

#define B_ 32
#define C_ 32
#define L_ 16384
#define H_ 4
#define DH_ 8
#define NB_ 3
#define DOUT_ 10
#define SEG_ 512
#define S_ (L_/SEG_)   // 32 segments for the standalone stats pass (block 0 input)
#define S2_ (L_/256)   // 64 segments for fused stats (one per block_kernel WG)

#define TILE 256
#define AST  40    // A_lds row stride (halfs): 80 B/row -> 16B-aligned b128 frag reads
#define OST  260   // O16 row stride (floats): 16B-aligned f32x4, banks spread by +4

typedef _Float16 f16_t;
typedef _Float16 f16x2 __attribute__((ext_vector_type(2)));
typedef _Float16 f16x8 __attribute__((ext_vector_type(8)));
typedef float    f32x4 __attribute__((ext_vector_type(4)));

// Branch-free gelu via Abramowitz-Stegun 7.1.26 erf approximation (|eps|<=1.5e-7).
__device__ __forceinline__ float gelu_f(float x){
    const float z  = fabsf(x) * 0.70710678118654752440f;
    const float t  = __builtin_amdgcn_rcpf(fmaf(0.3275911f, z, 1.0f));
    const float e  = __expf(-z * z);
    float p = fmaf(t, 1.061405429f, -1.453152027f);
    p = fmaf(t, p, 1.421413741f);
    p = fmaf(t, p, -0.284496736f);
    p = fmaf(t, p, 0.254829592f);
    const float erfz = 1.0f - p * t * e;          // erf(|x|/sqrt(2))
    const float phi  = fmaf(copysignf(erfz, x), 0.5f, 0.5f);
    return x * phi;
}

#define RED_MAX32(v) do{ v = fmaxf(v, __shfl_xor(v,1));  v = fmaxf(v, __shfl_xor(v,2)); \
                         v = fmaxf(v, __shfl_xor(v,4));  v = fmaxf(v, __shfl_xor(v,8)); \
                         v = fmaxf(v, __shfl_xor(v,16)); }while(0)
#define RED_SUM32(v) do{ v += __shfl_xor(v,1);  v += __shfl_xor(v,2); \
                         v += __shfl_xor(v,4);  v += __shfl_xor(v,8); \
                         v += __shfl_xor(v,16); }while(0)

// ---- stats: per (b, head, seg) partial max / sumexp / kv over a 512-pos segment ----
// Only used for the raw input x (block 0). Blocks 1,2 get their stats fused into
// the previous block_kernel's epilogue (O16 already holds the output channel-major).
__global__ __launch_bounds__(256) void stats_kernel(const float* __restrict__ h,
                                                    float* __restrict__ part){
    const int seg = blockIdx.x;
    const int hd  = blockIdx.y;
    const int b   = blockIdx.z;
    const int t   = threadIdx.x;
    const int d   = t >> 5;   // 0..7  (feature within head); wave-half owns one d
    const int j   = t & 31;   // 0..31 (position lane)

    __shared__ float tile[8][SEG_];   // 16 KB
    __shared__ float sm[8];

    const float* hb = h + (size_t)b * ((size_t)C_*L_) + (size_t)(hd*DH_)*L_ + (size_t)seg*SEG_;

    // stage 8 x 512 tile (coalesced float4; each element fetched exactly once)
    for (int f = t; f < 8*SEG_/4; f += 256){
        const int row = f >> 7;            // 128 float4 per row
        const int c4  = (f & 127) << 2;
        *(f32x4*)&tile[row][c4] = *(const f32x4*)&hb[(size_t)row*L_ + c4];
    }
    __syncthreads();

    // pass 1: per-d max
    float m = -INFINITY;
    #pragma unroll
    for (int i = 0; i < SEG_/32; i++) m = fmaxf(m, tile[d][j + 32*i]);
    RED_MAX32(m);
    if (j == 0) sm[d] = m;
    const float m_d = m;

    // pass 2: sumexp + kv partials (referenced to segment max)
    float s = 0.0f;
    float kv[8];
    #pragma unroll
    for (int e = 0; e < 8; e++) kv[e] = 0.0f;
    #pragma unroll
    for (int i = 0; i < SEG_/32; i++){
        const int k = j + 32*i;
        const float ek = __expf(tile[d][k] - m_d);
        s += ek;
        #pragma unroll
        for (int e = 0; e < 8; e++) kv[e] = fmaf(ek, tile[e][k], kv[e]);
    }
    RED_SUM32(s);
    #pragma unroll
    for (int e = 0; e < 8; e++){ RED_SUM32(kv[e]); }
    __syncthreads();

    float* po = part + (size_t)((b*H_ + hd)*S_ + seg) * 80;
    if (j == 0){
        po[8 + d] = s;
        #pragma unroll
        for (int e = 0; e < 8; e++) po[16 + d*8 + e] = kv[e];
    }
    if (t < 8) po[t] = sm[t];
}

// ---- merge segment partials -> normalized kvn[b][head][d][e] = kv/s ----
// 256 threads: 4 segment-groups in parallel + LDS tree (the 64-thread serial
// version was a latency-bound dependent loop over all segments).
__global__ __launch_bounds__(256) void merge_kernel(const float* __restrict__ part,
                                                    float* __restrict__ kvn,
                                                    int nseg){
    const int bh = blockIdx.x;              // 0..B*H-1
    const int t  = threadIdx.x & 63;        // (d,e)
    const int g  = threadIdx.x >> 6;        // 0..3 segment group
    const int d  = t >> 3;
    const float* p = part + (size_t)bh * nseg * 80;
    __shared__ float r1[4][64], r2[4][64];

    float M = -INFINITY;
    for (int s2 = g; s2 < nseg; s2 += 4) M = fmaxf(M, p[s2*80 + d]);
    r1[g][t] = M;
    __syncthreads();
    M = fmaxf(fmaxf(r1[0][t], r1[1][t]), fmaxf(r1[2][t], r1[3][t]));
    __syncthreads();

    float ssum = 0.0f, kvsum = 0.0f;
    for (int s2 = g; s2 < nseg; s2 += 4){
        const float sc = __expf(p[s2*80 + d] - M);
        ssum  += p[s2*80 + 8  + d] * sc;
        kvsum += p[s2*80 + 16 + t] * sc;
    }
    r1[g][t] = ssum; r2[g][t] = kvsum;
    __syncthreads();
    if (g == 0){
        ssum  = r1[0][t]+r1[1][t]+r1[2][t]+r1[3][t];
        kvsum = r2[0][t]+r2[1][t]+r2[2][t]+r2[3][t];
        kvn[(size_t)bh*64 + t] = kvsum / ssum;
    }
}

// ---- per-position attention (fp32) + FC1/FC2 via f16 MFMA ----
// LDS 26112 (Ash aliased with O16) -> 6 WG/CU by LDS.
// OCCUPANCY NOTE (R1/R2 post-mortem): any amdgpu_waves_per_eu(min>=5) makes the
// allocator contract the ~75-reg live set to 40-48 VGPRs and spill to scratch
// (+30-55 MB/dispatch of pure spill traffic; dur 41->68-70 us). waves_per_eu(3,4)
// is the proven spill-free config (R0: VGPR=68, zero scratch). The max=4 arg only
// bounds the ALLOCATOR's assumption; runtime residency is resource-limited:
// 68 VGPR allows 7 waves/EU, LDS 26112 caps at 6 WG/CU (24 waves, 75%) --
// 2x the R0 residency, which is the occupancy win we were after.
// STATS: compute next block's per-segment softmax partials straight from O16
// (channel-major fp32, bit-identical to hout) -- removes the standalone 64 MB
// stats pass for blocks 1,2.
// MFMA layouts (m89/m91-verified conventions):
//   A-frag: lane holds A[m=lane&15][k=(lane>>4)*8+j], 8 halfs contiguous
//   B-frag: lane holds B[k=(lane>>4)*8+j][n=lane&15]  (stored as Bsh[n][k])
//   C/D:    col=lane&15, row=(lane>>4)*4+reg
template<bool LAST, bool STATS>
__global__ __launch_bounds__(256)
__attribute__((amdgpu_waves_per_eu(3, 4)))
void block_kernel(const float* hin,
                  float* hout,
                  const float* __restrict__ kvn,
                  const float* __restrict__ W1,
                  const float* __restrict__ b1,
                  const float* __restrict__ W2,
                  const float* __restrict__ b2,
                  float* __restrict__ pooled,
                  float* __restrict__ partout){
    __shared__ __align__(16) char AObuf[TILE*AST*2];   // 20480 B, union:
    f16_t* const Ash = (f16_t*)AObuf;                  //   A matrix [pos][k] halfs
    float* const O16 = (float*)AObuf;                  //   16-chan transpose buffer (16640 B)
    __shared__ f16_t Bsh1[32*AST];      // 2560 B: W1 as [n][k]
    __shared__ f16_t Bsh2[32*AST];      // 2560 B
    __shared__ float sb1[32], sb2[32];
    __shared__ float pool[32];

    const int tid = threadIdx.x;
    const int b   = blockIdx.y;
    const int l0  = blockIdx.x * TILE;
    const int l   = l0 + tid;
    const size_t base = (size_t)b * ((size_t)C_*L_);
    const float* kv = kvn + (size_t)b * (H_*DH_*DH_);

    // stage weights f32->f16 into B-layout: Bsh[n][k] = W[k*32+n]
    for (int i = tid; i < 1024; i += 256){
        const int k = i >> 5, n = i & 31;
        Bsh1[n*AST + k] = (f16_t)W1[i];
        Bsh2[n*AST + k] = (f16_t)W2[i];
    }
    if (tid < 32){ sb1[tid] = b1[tid]; sb2[tid] = b2[tid]; }
    if (LAST && tid < 32) pool[tid] = 0.0f;

    // ---- phase 1: per-thread fp32 attention ----
    float h[32];
    #pragma unroll
    for (int c = 0; c < 32; c++) h[c] = hin[base + (size_t)c*L_ + l];

    float attn[32];
    #pragma unroll
    for (int hh = 0; hh < 4; hh++){
        float mq = h[hh*8];
        #pragma unroll
        for (int d2 = 1; d2 < 8; d2++) mq = fmaxf(mq, h[hh*8 + d2]);
        float es[8]; float qs = 0.f;
        #pragma unroll
        for (int d2 = 0; d2 < 8; d2++){ es[d2] = __expf(h[hh*8 + d2] - mq); qs += es[d2]; }
        const float inv = __builtin_amdgcn_rcpf(qs);
        #pragma unroll
        for (int e = 0; e < 8; e++){
            float a = 0.f;
            #pragma unroll
            for (int d2 = 0; d2 < 8; d2++) a += es[d2] * kv[hh*64 + d2*8 + e];
            attn[hh*8 + e] = a * inv;
        }
    }

    // attn -> f16 A matrix in LDS: Ash[pos=tid][k]
    #pragma unroll
    for (int k2 = 0; k2 < 32; k2 += 2){
        f16x2 pr = { (f16_t)attn[k2], (f16_t)attn[k2+1] };
        *(f16x2*)&Ash[tid*AST + k2] = pr;
    }
    __syncthreads();   // weights + A visible to all

    // ---- phase 2: MFMA FCs ----
    const int wv   = tid >> 6;       // wave 0..3 -> positions [wv*64, wv*64+64)
    const int lane = tid & 63;
    const int lr   = lane & 15;      // A-row / D-col index
    const int lk   = lane >> 4;      // k-group 0..3
    const f32x4 zero = {0.f, 0.f, 0.f, 0.f};

    f16x8 a[4], bw[2];
    f32x4 d[8];

    // FC1
    #pragma unroll
    for (int mt = 0; mt < 4; mt++)
        a[mt] = *(const f16x8*)&Ash[(wv*64 + mt*16 + lr)*AST + lk*8];
    #pragma unroll
    for (int nt = 0; nt < 2; nt++)
        bw[nt] = *(const f16x8*)&Bsh1[(nt*16 + lr)*AST + lk*8];
    #pragma unroll
    for (int nt = 0; nt < 2; nt++)
        #pragma unroll
        for (int mt = 0; mt < 4; mt++)
            d[nt*4+mt] = __builtin_amdgcn_mfma_f32_16x16x32_f16(a[mt], bw[nt], zero, 0, 0, 0);

    // bias + gelu + write back as A2 (in-place over Ash; rows are wave-private)
    #pragma unroll
    for (int nt = 0; nt < 2; nt++){
        const float bias = sb1[nt*16 + lr];
        #pragma unroll
        for (int mt = 0; mt < 4; mt++){
            #pragma unroll
            for (int r = 0; r < 4; r++){
                const float v = gelu_f(d[nt*4+mt][r] + bias);
                Ash[(wv*64 + mt*16 + lk*4 + r)*AST + (nt*16 + lr)] = (f16_t)v;
            }
        }
    }
    __syncthreads();

    // FC2
    #pragma unroll
    for (int mt = 0; mt < 4; mt++)
        a[mt] = *(const f16x8*)&Ash[(wv*64 + mt*16 + lr)*AST + lk*8];
    #pragma unroll
    for (int nt = 0; nt < 2; nt++)
        bw[nt] = *(const f16x8*)&Bsh2[(nt*16 + lr)*AST + lk*8];
    #pragma unroll
    for (int nt = 0; nt < 2; nt++)
        #pragma unroll
        for (int mt = 0; mt < 4; mt++)
            d[nt*4+mt] = __builtin_amdgcn_mfma_f32_16x16x32_f16(a[mt], bw[nt], zero, 0, 0, 0);

    // bias + gelu on D (fp32)
    #pragma unroll
    for (int nt = 0; nt < 2; nt++){
        const float bias = sb2[nt*16 + lr];
        #pragma unroll
        for (int mt = 0; mt < 4; mt++)
            #pragma unroll
            for (int r = 0; r < 4; r++)
                d[nt*4+mt][r] = gelu_f(d[nt*4+mt][r] + bias);
    }

    if (!LAST){
        // transpose D -> [chan][pos] via LDS (aliases Ash; Ash reads all complete
        // before the leading barrier). While the O16 half-tile is live, also
        // compute next-block stats partials from it (fused stats).
        #pragma unroll
        for (int nt = 0; nt < 2; nt++){
            __syncthreads();   // previous O16 consumers done / Ash dead
            #pragma unroll
            for (int mt = 0; mt < 4; mt++)
                *(f32x4*)&O16[lr*OST + wv*64 + mt*16 + lk*4] = d[nt*4+mt];
            __syncthreads();
            #pragma unroll
            for (int c = 0; c < 16; c++)
                hout[base + (size_t)(nt*16 + c)*L_ + l0 + tid] = O16[c*OST + tid];

            if constexpr (STATS){
                // O16[r16][pos]: channels nt*16+r16, heads nt*2 + (r16>>3).
                // Same math as stats_kernel, segment = this WG's 256 positions.
                const int sd = tid >> 5;   // 0..7 feature
                const int sj = tid & 31;   // position lane
                #pragma unroll
                for (int hh2 = 0; hh2 < 2; hh2++){
                    const int row = hh2*8 + sd;
                    float m = -INFINITY;
                    #pragma unroll
                    for (int i = 0; i < 8; i++) m = fmaxf(m, O16[row*OST + sj + 32*i]);
                    RED_MAX32(m);
                    float s = 0.0f;
                    float kvp[8];
                    #pragma unroll
                    for (int e = 0; e < 8; e++) kvp[e] = 0.0f;
                    #pragma unroll
                    for (int i = 0; i < 8; i++){
                        const int k = sj + 32*i;
                        const float ek = __expf(O16[row*OST + k] - m);
                        s += ek;
                        #pragma unroll
                        for (int e = 0; e < 8; e++)
                            kvp[e] = fmaf(ek, O16[(hh2*8+e)*OST + k], kvp[e]);
                    }
                    RED_SUM32(s);
                    #pragma unroll
                    for (int e = 0; e < 8; e++){ RED_SUM32(kvp[e]); }
                    if (sj == 0){
                        float* po = partout +
                            (size_t)((b*H_ + nt*2 + hh2)*S2_ + blockIdx.x) * 80;
                        po[sd]     = m;
                        po[8 + sd] = s;
                        #pragma unroll
                        for (int e = 0; e < 8; e++) po[16 + sd*8 + e] = kvp[e];
                    }
                }
            }
        }
    } else {
        // pooled += sum over this WG's 256 positions
        __syncthreads();   // pool[] initialized
        #pragma unroll
        for (int nt = 0; nt < 2; nt++){
            float ps = 0.f;
            #pragma unroll
            for (int mt = 0; mt < 4; mt++)
                ps += d[nt*4+mt][0] + d[nt*4+mt][1] + d[nt*4+mt][2] + d[nt*4+mt][3];
            atomicAdd(&pool[nt*16 + lr], ps);
        }
        __syncthreads();
        if (tid < 32) atomicAdd(&pooled[b*32 + tid], pool[tid]);
    }
}

// ---- head: pooled/L -> Wh+bh -> BN(eval) -> gelu -> Wf+bf ----
__global__ __launch_bounds__(1024) void head_kernel(const float* __restrict__ pooled,
                                                    const float* __restrict__ Wh,
                                                    const float* __restrict__ bh,
                                                    const float* __restrict__ gam,
                                                    const float* __restrict__ bet,
                                                    const float* __restrict__ mean,
                                                    const float* __restrict__ var,
                                                    const float* __restrict__ Wf,
                                                    const float* __restrict__ bf,
                                                    float* __restrict__ out){
    __shared__ float y2[32][32];
    const int t = threadIdx.x;      // 0..1023
    const int b = t >> 5, c = t & 31;
    float a = bh[c];
    const float invL = 1.0f / (float)L_;
    #pragma unroll
    for (int d = 0; d < 32; d++) a += (pooled[b*32 + d] * invL) * Wh[d*32 + c];
    a = (a - mean[c]) * rsqrtf(var[c] + 1e-5f) * gam[c] + bet[c];
    y2[b][c] = gelu_f(a);
    __syncthreads();
    if (t < B_*DOUT_){
        const int b2 = t / DOUT_, j = t % DOUT_;
        float r = bf[j];
        #pragma unroll
        for (int c2 = 0; c2 < 32; c2++) r += y2[b2][c2] * Wf[c2*DOUT_ + j];
        out[t] = r;
    }
}

extern "C" void kernel_launch(void* const* d_in, const int* in_sizes, int n_in,
                              void* d_out, int out_size, void* d_ws, size_t ws_size,
                              hipStream_t stream){
    (void)in_sizes; (void)n_in; (void)out_size; (void)ws_size;
    const float* x    = (const float*)d_in[0];
    const float* fW1  = (const float*)d_in[1];
    const float* fb1  = (const float*)d_in[2];
    const float* fW2  = (const float*)d_in[3];
    const float* fb2  = (const float*)d_in[4];
    const float* Wh   = (const float*)d_in[5];
    const float* bh   = (const float*)d_in[6];
    const float* gam  = (const float*)d_in[7];
    const float* bet  = (const float*)d_in[8];
    const float* mean = (const float*)d_in[9];
    const float* var  = (const float*)d_in[10];
    const float* Wf   = (const float*)d_in[11];
    const float* bf   = (const float*)d_in[12];
    float* out = (float*)d_out;

    float* hbuf   = (float*)d_ws;                          // B*C*L floats (64 MB)
    float* part   = hbuf + (size_t)B_*C_*L_;               // B*H*S2_*80 (~2.6 MB)
    float* kvn    = part + (size_t)B_*H_*S2_*80;           // B*H*64
    float* pooled = kvn  + (size_t)B_*H_*64;               // B*C

    hipMemsetAsync(pooled, 0, B_*C_*sizeof(float), stream);

    dim3 sgrid(S_, H_, B_);
    dim3 bgrid(L_/TILE, B_);

    // block 0 (input = x, output -> hbuf; fused stats for block 1 -> part)
    stats_kernel<<<sgrid, 256, 0, stream>>>(x, part);
    merge_kernel<<<B_*H_, 256, 0, stream>>>(part, kvn, S_);
    block_kernel<false, true><<<bgrid, 256, 0, stream>>>(x, hbuf, kvn,
        fW1, fb1, fW2, fb2, nullptr, part);
    // block 1 (in-place on hbuf; fused stats for block 2 -> part)
    merge_kernel<<<B_*H_, 256, 0, stream>>>(part, kvn, S2_);
    block_kernel<false, true><<<bgrid, 256, 0, stream>>>(hbuf, hbuf, kvn,
        fW1 + C_*C_, fb1 + C_, fW2 + C_*C_, fb2 + C_, nullptr, part);
    // block 2 (no h write; reduce into pooled)
    merge_kernel<<<B_*H_, 256, 0, stream>>>(part, kvn, S2_);
    block_kernel<true, false><<<bgrid, 256, 0, stream>>>(hbuf, nullptr, kvn,
        fW1 + 2*C_*C_, fb1 + 2*C_, fW2 + 2*C_*C_, fb2 + 2*C_, pooled, nullptr);

    head_kernel<<<1, 1024, 0, stream>>>(pooled, Wh, bh, gam, bet, mean, var, Wf, bf, out);
}